// Round 2
// baseline (2429.347 us; speedup 1.0000x reference)
//
#include <hip/hip_runtime.h>
#include <cfloat>

// VectorQuantizer: N=32768 rows, K=8192 codes, D=256, fp32.
// Strategy: REPLICATE numpy's fp32 reference arithmetic bit-for-bit where it
// matters, because the fp32 distances (magnitude ~256, ulp 3.05e-5) quantize
// away top-2 gaps (~5.6e-4) on ~1-2% of rows — the true argmin differs from
// the fp32 reference argmin on hundreds of rows.
//   d_k = fl32( fl32(x2 + wn_k) - fl32(2*m_k) ),  argmin = first occurrence.
// m_k: BLAS sgemm accumulates one fp32 FMA chain over k ascending -> our tiled
// accumulator reproduces it exactly (single fmaf chain, d ascending).
// x2 errors are row-uniform ulp shifts (argmin-invariant); wn errors ~1e-13
// (irrelevant); both still emulated with numpy's scalar pairwise order.

#define DDIM 256
#define BM 64
#define BN 64
#define BD 32
#define XPITCH 260   // +4 pad
#define WPITCH 36    // +4 pad
#define NTHREADS 256

struct Cand { float d; int k; };

// numpy pairwise_sum of fl(a[i]*a[i]) for n=256 contiguous:
// pairwise(256) = pairwise(a,128) + pairwise(a+128,128); each 128-block uses
// 8 stride-8 accumulators combined ((r0+r1)+(r2+r3))+((r4+r5)+(r6+r7)).
// __fmul_rn/__fadd_rn block fp-contraction (numpy does mul then add, no fma).
__device__ __forceinline__ float np_sumsq256(const float* __restrict__ p) {
    float half[2];
#pragma unroll
    for (int h = 0; h < 2; ++h) {
        const float* a = p + h * 128;
        float r[8];
#pragma unroll
        for (int j = 0; j < 8; ++j) r[j] = __fmul_rn(a[j], a[j]);
        for (int i = 8; i < 128; i += 8)
#pragma unroll
            for (int j = 0; j < 8; ++j)
                r[j] = __fadd_rn(r[j], __fmul_rn(a[i + j], a[i + j]));
        float s01 = __fadd_rn(r[0], r[1]);
        float s23 = __fadd_rn(r[2], r[3]);
        float s45 = __fadd_rn(r[4], r[5]);
        float s67 = __fadd_rn(r[6], r[7]);
        half[h] = __fadd_rn(__fadd_rn(s01, s23), __fadd_rn(s45, s67));
    }
    return __fadd_rn(half[0], half[1]);
}

__global__ __launch_bounds__(256) void vq_norms(
    const float* __restrict__ x, const float* __restrict__ w,
    float* __restrict__ x2, float* __restrict__ wn, int N, int K) {
    int t = blockIdx.x * 256 + threadIdx.x;
    if (t < N) {
        x2[t] = np_sumsq256(x + (size_t)t * DDIM);
    } else if (t < N + K) {
        int k = t - N;
        wn[k] = np_sumsq256(w + (size_t)k * DDIM);
    }
}

__global__ __launch_bounds__(NTHREADS) void vq_score_argmin(
    const float* __restrict__ x, const float* __restrict__ w,
    const float* __restrict__ x2, const float* __restrict__ wn,
    int* __restrict__ candOut, int K) {
    __shared__ float xs[BM * XPITCH];   // 66560 B (reused as Cand merge buf)
    __shared__ float wsh[BN * WPITCH];  //  9216 B
    const int tid = threadIdx.x;
    const int tx = tid & 15, ty = tid >> 4;
    const int rowBase = blockIdx.x * BM;

    // Stage X tile (contiguous 64 KB, coalesced float4)
    {
        const float4* gx = reinterpret_cast<const float4*>(x + (size_t)rowBase * DDIM);
        for (int idx = tid; idx < BM * (DDIM / 4); idx += NTHREADS) {
            int r = idx >> 6;
            int c = idx & 63;
            *reinterpret_cast<float4*>(&xs[r * XPITCH + c * 4]) = gx[idx];
        }
    }

    float x2r[4];
#pragma unroll
    for (int i = 0; i < 4; ++i) x2r[i] = x2[rowBase + ty + 16 * i];

    float bD[4]; int bK[4];
#pragma unroll
    for (int i = 0; i < 4; ++i) { bD[i] = FLT_MAX; bK[i] = 0x7fffffff; }

    for (int kt = 0; kt < K; kt += BN) {
        float acc[4][4];
#pragma unroll
        for (int i = 0; i < 4; ++i)
#pragma unroll
            for (int j = 0; j < 4; ++j) acc[i][j] = 0.f;

        for (int d0 = 0; d0 < DDIM; d0 += BD) {
            __syncthreads();  // covers xs staging on first pass, wsh reuse after
            for (int idx = tid; idx < BN * (BD / 4); idx += NTHREADS) {
                int r = idx >> 3;
                int c = idx & 7;
                *reinterpret_cast<float4*>(&wsh[r * WPITCH + c * 4]) =
                    *reinterpret_cast<const float4*>(
                        w + (size_t)(kt + r) * DDIM + d0 + c * 4);
            }
            __syncthreads();
            // Single fp32 FMA chain per (row,k), d strictly ascending —
            // bit-identical to BLAS sgemm microkernel accumulation.
#pragma unroll
            for (int dd = 0; dd < BD; dd += 4) {
                float4 xv[4], wv[4];
#pragma unroll
                for (int i = 0; i < 4; ++i)
                    xv[i] = *reinterpret_cast<const float4*>(
                        &xs[(ty + 16 * i) * XPITCH + d0 + dd]);
#pragma unroll
                for (int j = 0; j < 4; ++j)
                    wv[j] = *reinterpret_cast<const float4*>(
                        &wsh[(tx + 16 * j) * WPITCH + dd]);
#pragma unroll
                for (int i = 0; i < 4; ++i)
#pragma unroll
                    for (int j = 0; j < 4; ++j) {
                        acc[i][j] = __fmaf_rn(xv[i].x, wv[j].x, acc[i][j]);
                        acc[i][j] = __fmaf_rn(xv[i].y, wv[j].y, acc[i][j]);
                        acc[i][j] = __fmaf_rn(xv[i].z, wv[j].z, acc[i][j]);
                        acc[i][j] = __fmaf_rn(xv[i].w, wv[j].w, acc[i][j]);
                    }
            }
        }
        // Emulated numpy combine: fl(fl(x2+wn) - fl(2*m)); k ascending scan
        // with strict < keeps first occurrence (np.argmin semantics).
#pragma unroll
        for (int j = 0; j < 4; ++j) {
            int   kj  = kt + tx + 16 * j;
            float wnj = wn[kj];
#pragma unroll
            for (int i = 0; i < 4; ++i) {
                float t1 = __fadd_rn(x2r[i], wnj);
                float dv = __fsub_rn(t1, __fmul_rn(2.0f, acc[i][j]));
                if (dv < bD[i] || (dv == bD[i] && kj < bK[i])) {
                    bD[i] = dv; bK[i] = kj;
                }
            }
        }
    }

    // Merge 16 threads per row: lexicographic (d, k) min = first global min
    __syncthreads();
    Cand* cl = reinterpret_cast<Cand*>(xs);
#pragma unroll
    for (int i = 0; i < 4; ++i) {
        int r = ty + 16 * i;
        cl[r * 16 + tx] = Cand{bD[i], bK[i]};
    }
    __syncthreads();
    if (tid < BM) {
        Cand best = cl[tid * 16];
        for (int e = 1; e < 16; ++e) {
            Cand c = cl[tid * 16 + e];
            if (c.d < best.d || (c.d == best.d && c.k < best.k)) best = c;
        }
        candOut[rowBase + tid] = best.k;
    }
}

__global__ __launch_bounds__(256) void vq_gather_write(
    const float* __restrict__ w, const int* __restrict__ cand,
    float* __restrict__ outq, float* __restrict__ outi, int N) {
    int gid  = blockIdx.x * blockDim.x + threadIdx.x;
    int row  = gid >> 6;
    int lane = threadIdx.x & 63;
    if (row >= N) return;
    int k = cand[row];
    float4 qv = *reinterpret_cast<const float4*>(w + (size_t)k * DDIM + lane * 4);
    *reinterpret_cast<float4*>(outq + (size_t)row * DDIM + lane * 4) = qv;
    if (lane == 0) outi[row] = (float)k;
}

extern "C" void kernel_launch(void* const* d_in, const int* in_sizes, int n_in,
                              void* d_out, int out_size, void* d_ws, size_t ws_size,
                              hipStream_t stream) {
    const float* x = (const float*)d_in[0];
    const float* w = (const float*)d_in[1];
    const int N = in_sizes[0] / DDIM;   // 32768
    const int K = in_sizes[1] / DDIM;   // 8192
    float* outq = (float*)d_out;
    float* outi = outq + (size_t)N * DDIM;

    float* x2   = (float*)d_ws;                                   // N floats
    float* wn   = x2 + N;                                          // K floats
    int*   cand = (int*)(wn + K);                                  // N ints

    hipLaunchKernelGGL(vq_norms, dim3((N + K + 255) / 256), dim3(256), 0, stream,
                       x, w, x2, wn, N, K);
    hipLaunchKernelGGL(vq_score_argmin, dim3(N / BM), dim3(NTHREADS), 0, stream,
                       x, w, x2, wn, cand, K);
    hipLaunchKernelGGL(vq_gather_write, dim3((N * 64 + 255) / 256), dim3(256), 0, stream,
                       w, cand, outq, outi, N);
}

// Round 3
// 362.350 us; speedup vs baseline: 6.7044x; 6.7044x over previous
//
#include <hip/hip_runtime.h>
#include <cfloat>

// VectorQuantizer: N=32768 rows, K=8192 codes, D=256, fp32.
// R2 established: reference argmin follows numpy fp32 arithmetic
//   d_k = fl32( fl32(x2 + wn_k) - fl32(2*m_k) ), m_k = single fp32 FMA chain
//   over d ascending (BLAS sgemm), first-occurrence argmin.  (absmax == 0)
// R3 strategy: bf16 MFMA approximate scoring (2.5 PF pipe) with fused per-row
// candidate tracking; exact fp32-chain rescore of top-8 candidates per row.
// bf16 score error sigma ~2e-5 << per-row score spacing ~1e-3 (validated by
// R0: fp32-ulp 3e-5 perturbations flip only ~0.5% rows) -> P(true argmin
// outside top-8 of 128 kept candidates) < 1e-9 over all rows.

#define DDIM 256

typedef float f32x4 __attribute__((ext_vector_type(4)));
typedef short bf16x8 __attribute__((ext_vector_type(8)));   // 8 bf16 in 4 VGPRs

// ---------- exact RNE float -> bf16 bits (no header dependence) ----------
__device__ __forceinline__ unsigned short f2bf(float f) {
    unsigned u = __float_as_uint(f);
    u += 0x7FFFu + ((u >> 16) & 1u);   // round-to-nearest-even
    return (unsigned short)(u >> 16);
}

// ---------- numpy pairwise sum-of-squares (verified bit-exact in R2) ----------
__device__ __forceinline__ float np_sumsq256(const float* __restrict__ p) {
    float half[2];
#pragma unroll
    for (int h = 0; h < 2; ++h) {
        const float* a = p + h * 128;
        float r[8];
#pragma unroll
        for (int j = 0; j < 8; ++j) r[j] = __fmul_rn(a[j], a[j]);
        for (int i = 8; i < 128; i += 8)
#pragma unroll
            for (int j = 0; j < 8; ++j)
                r[j] = __fadd_rn(r[j], __fmul_rn(a[i + j], a[i + j]));
        float s01 = __fadd_rn(r[0], r[1]);
        float s23 = __fadd_rn(r[2], r[3]);
        float s45 = __fadd_rn(r[4], r[5]);
        float s67 = __fadd_rn(r[6], r[7]);
        half[h] = __fadd_rn(__fadd_rn(s01, s23), __fadd_rn(s45, s67));
    }
    return __fadd_rn(half[0], half[1]);
}

__global__ __launch_bounds__(256) void vq_norms(
    const float* __restrict__ x, const float* __restrict__ w,
    float* __restrict__ x2, float* __restrict__ wn, int N, int K) {
    int t = blockIdx.x * 256 + threadIdx.x;
    if (t < N) {
        x2[t] = np_sumsq256(x + (size_t)t * DDIM);
    } else if (t < N + K) {
        int k = t - N;
        wn[k] = np_sumsq256(w + (size_t)k * DDIM);
    }
}

// ---------- W fp32 -> bf16 (row-major, pitch 256) ----------
__global__ __launch_bounds__(256) void vq_wcvt(
    const float* __restrict__ w, unsigned short* __restrict__ wb, int total4) {
    int i = blockIdx.x * 256 + threadIdx.x;
    if (i >= total4) return;
    float4 f = *reinterpret_cast<const float4*>(w + (size_t)i * 4);
    ushort4 o;
    o.x = f2bf(f.x); o.y = f2bf(f.y); o.z = f2bf(f.z); o.w = f2bf(f.w);
    *reinterpret_cast<ushort4*>(wb + (size_t)i * 4) = o;
}

// ---------- bf16 MFMA scoring + fused top-candidate tracking ----------
// Block: 512 threads = 8 waves (2 row-groups x 4 col-groups).
// Block tile: 128 rows x 128 cols per col-tile iteration, 64 col-tiles.
// D processed in 2 chunks of 128 (LDS: Xs 32 KB + Ws 32 KB = 64 KB, swizzled
// XOR layout -> conflict-free ds_read_b128, no padding so 16B groups align).
// Wave tile: 64 rows x 32 cols = 4x2 MFMA tiles of 16x16, K=32 per mfma.
// Fragment layouts (learn_hip m89/m120 verified):
//   A: row m = lane&15, k = (lane>>4)*8 + j   (8 contiguous bf16 = 16B load)
//   B: col n = lane&15, k = (lane>>4)*8 + j
//   C: col  = lane&15, row = (lane>>4)*4 + reg
__global__ __launch_bounds__(512) void vq_score_mfma(
    const float* __restrict__ x, const unsigned short* __restrict__ wb,
    unsigned* __restrict__ cand, int K) {
    __shared__ unsigned smem[16384];                    // 64 KB
    unsigned short* Xs = (unsigned short*)smem;         // [128][128] swizzled
    unsigned short* Ws = (unsigned short*)(smem + 8192);

    const int tid  = threadIdx.x;
    const int wave = tid >> 6, lane = tid & 63;
    const int wr = wave >> 2, wc = wave & 3;            // 2 x 4 wave grid
    const int q  = lane >> 4, c = lane & 15;
    const int rowBase = blockIdx.x * 128;

    f32x4 acc[4][2];
    unsigned s0[4][4], s1[4][4];
#pragma unroll
    for (int a = 0; a < 4; ++a)
#pragma unroll
        for (int b = 0; b < 4; ++b) { s0[a][b] = 0xFFFFFFFFu; s1[a][b] = 0xFFFFFFFFu; }

    const int sg = tid & 15;        // staging group index 0..15 (16B granules)
    const int sr0 = tid >> 4;       // staging row 0..31 (x4 passes)

    for (int kt = 0; kt < 64; ++kt) {
#pragma unroll
        for (int rt = 0; rt < 4; ++rt)
#pragma unroll
            for (int ct = 0; ct < 2; ++ct) acc[rt][ct] = (f32x4){0.f, 0.f, 0.f, 0.f};

        for (int chunk = 0; chunk < 2; ++chunk) {
            __syncthreads();
            // ---- stage X chunk: fp32 global -> bf16 LDS (swizzled) ----
            {
                const int d0 = chunk * 128 + sg * 8;
#pragma unroll
                for (int p = 0; p < 4; ++p) {
                    int r = sr0 + p * 32;
                    const float4* src = reinterpret_cast<const float4*>(
                        x + (size_t)(rowBase + r) * DDIM + d0);
                    float4 f0 = src[0], f1 = src[1];
                    ushort4 lo, hi;
                    lo.x = f2bf(f0.x); lo.y = f2bf(f0.y); lo.z = f2bf(f0.z); lo.w = f2bf(f0.w);
                    hi.x = f2bf(f1.x); hi.y = f2bf(f1.y); hi.z = f2bf(f1.z); hi.w = f2bf(f1.w);
                    unsigned short* dst = Xs + r * 128 + ((sg ^ (r & 15)) * 8);
                    *reinterpret_cast<ushort4*>(dst)     = lo;
                    *reinterpret_cast<ushort4*>(dst + 4) = hi;
                }
            }
            // ---- stage W chunk: bf16 global -> LDS (swizzled) ----
            {
                const int d0 = chunk * 128 + sg * 8;
#pragma unroll
                for (int p = 0; p < 4; ++p) {
                    int r = sr0 + p * 32;
                    uint4 v = *reinterpret_cast<const uint4*>(
                        wb + (size_t)(kt * 128 + r) * DDIM + d0);
                    *reinterpret_cast<uint4*>(Ws + r * 128 + ((sg ^ (r & 15)) * 8)) = v;
                }
            }
            __syncthreads();
            // ---- 4 k-steps of MFMA ----
#pragma unroll
            for (int ks = 0; ks < 4; ++ks) {
                const int goff = (((ks * 4 + q) ^ c) * 8);   // ushort offset
                bf16x8 af[4], bf[2];
#pragma unroll
                for (int rt = 0; rt < 4; ++rt)
                    af[rt] = *reinterpret_cast<const bf16x8*>(
                        Xs + (wr * 64 + rt * 16 + c) * 128 + goff);
#pragma unroll
                for (int ct = 0; ct < 2; ++ct)
                    bf[ct] = *reinterpret_cast<const bf16x8*>(
                        Ws + (wc * 32 + ct * 16 + c) * 128 + goff);
#pragma unroll
                for (int rt = 0; rt < 4; ++rt)
#pragma unroll
                    for (int ct = 0; ct < 2; ++ct)
                        acc[rt][ct] = __builtin_amdgcn_mfma_f32_16x16x32_bf16(
                            af[rt], bf[ct], acc[rt][ct], 0, 0, 0);
            }
        }
        // ---- fused selection: keep 2 smallest keys per (lane,row-slot) ----
        // key = sortable_u32(-m) truncated to 19 bits | 13-bit col index.
#pragma unroll
        for (int ct = 0; ct < 2; ++ct) {
            const unsigned colv = (unsigned)(kt * 128 + wc * 32 + ct * 16 + c);
#pragma unroll
            for (int rt = 0; rt < 4; ++rt)
#pragma unroll
                for (int rg = 0; rg < 4; ++rg) {
                    unsigned u = __float_as_uint(-acc[rt][ct][rg]);
                    u ^= (unsigned)(((int)u >> 31) | (int)0x80000000);
                    unsigned key = (u & 0xFFFFE000u) | colv;
                    unsigned t0 = s0[rt][rg], t1 = s1[rt][rg];
                    unsigned hi = key > t0 ? key : t0;
                    s0[rt][rg] = key < t0 ? key : t0;
                    s1[rt][rg] = hi  < t1 ? hi  : t1;
                }
        }
    }

    // ---- per-row merge: 8 waves x 16 lanes x 2 keys = 128 keys/row ----
    __syncthreads();
#pragma unroll
    for (int rt = 0; rt < 4; ++rt)
#pragma unroll
        for (int rg = 0; rg < 4; ++rg) {
            int row = wr * 64 + rt * 16 + q * 4 + rg;
            unsigned base = row * 128 + (wc * 16 + c) * 2;
            smem[base]     = s0[rt][rg];
            smem[base + 1] = s1[rt][rg];
        }
    __syncthreads();
    if (tid < 128) {
        const unsigned* rowk = smem + tid * 128;
        unsigned best[8];
#pragma unroll
        for (int i = 0; i < 8; ++i) best[i] = 0xFFFFFFFFu;
        for (int i = 0; i < 128; ++i) {
            unsigned key = rowk[i];
            if (key < best[7]) {
                best[7] = key;
#pragma unroll
                for (int j = 7; j > 0; --j)
                    if (best[j] < best[j - 1]) {
                        unsigned t = best[j]; best[j] = best[j - 1]; best[j - 1] = t;
                    }
            }
        }
        unsigned* out = cand + (size_t)(rowBase + tid) * 8;
#pragma unroll
        for (int i = 0; i < 8; ++i) out[i] = best[i];
    }
}

// ---------- exact fp32-chain rescore of 8 candidates + gather + write ----------
__global__ __launch_bounds__(256) void vq_rescore_write(
    const float* __restrict__ x, const float* __restrict__ w,
    const float* __restrict__ x2, const float* __restrict__ wn,
    const unsigned* __restrict__ cand, float* __restrict__ outq,
    float* __restrict__ outi) {
    __shared__ int winners[32];
    const int tid = threadIdx.x;
    const int lr = tid >> 3, cc = tid & 7;
    const int row = blockIdx.x * 32 + lr;

    int k = (int)(cand[(size_t)row * 8 + cc] & 0x1FFFu);
    const float* xr = x + (size_t)row * DDIM;
    const float* wr = w + (size_t)k * DDIM;
    // EXACT chain: single fp32 fmaf chain, d ascending (matches BLAS, R2-verified)
    float acc = 0.f;
#pragma unroll 8
    for (int d = 0; d < DDIM; d += 4) {
        float4 xv = *reinterpret_cast<const float4*>(xr + d);
        float4 wv = *reinterpret_cast<const float4*>(wr + d);
        acc = __fmaf_rn(xv.x, wv.x, acc);
        acc = __fmaf_rn(xv.y, wv.y, acc);
        acc = __fmaf_rn(xv.z, wv.z, acc);
        acc = __fmaf_rn(xv.w, wv.w, acc);
    }
    float dv = __fsub_rn(__fadd_rn(x2[row], wn[k]), __fmul_rn(2.0f, acc));
    // lexicographic (dv, k) min across the 8 candidate lanes (first-occurrence)
#pragma unroll
    for (int m = 1; m < 8; m <<= 1) {
        float od = __shfl_xor(dv, m, 64);
        int   ok = __shfl_xor(k,  m, 64);
        if (od < dv || (od == dv && ok < k)) { dv = od; k = ok; }
    }
    if (cc == 0) winners[lr] = k;
    __syncthreads();
    if (tid < 32) outi[blockIdx.x * 32 + tid] = (float)winners[tid];
    for (int u = tid; u < 32 * 64; u += 256) {
        int r = u >> 6, c4 = u & 63;
        *reinterpret_cast<float4*>(outq + (size_t)(blockIdx.x * 32 + r) * DDIM + c4 * 4) =
            *reinterpret_cast<const float4*>(w + (size_t)winners[r] * DDIM + c4 * 4);
    }
}

extern "C" void kernel_launch(void* const* d_in, const int* in_sizes, int n_in,
                              void* d_out, int out_size, void* d_ws, size_t ws_size,
                              hipStream_t stream) {
    const float* x = (const float*)d_in[0];
    const float* w = (const float*)d_in[1];
    const int N = in_sizes[0] / DDIM;   // 32768
    const int K = in_sizes[1] / DDIM;   // 8192
    float* outq = (float*)d_out;
    float* outi = outq + (size_t)N * DDIM;

    // workspace layout
    char* ws = (char*)d_ws;
    unsigned short* wb = (unsigned short*)ws;                 // K*256 bf16 = 4 MB
    float* x2   = (float*)(ws + (size_t)K * DDIM * 2);        // N floats
    float* wn   = x2 + N;                                     // K floats
    unsigned* cand = (unsigned*)(wn + K);                     // N*8 u32 = 1 MB

    hipLaunchKernelGGL(vq_norms, dim3((N + K + 255) / 256), dim3(256), 0, stream,
                       x, w, x2, wn, N, K);
    hipLaunchKernelGGL(vq_wcvt, dim3((K * DDIM / 4 + 255) / 256), dim3(256), 0, stream,
                       w, wb, K * DDIM / 4);
    hipLaunchKernelGGL(vq_score_mfma, dim3(N / 128), dim3(512), 0, stream,
                       x, wb, cand, K);
    hipLaunchKernelGGL(vq_rescore_write, dim3(N / 32), dim3(256), 0, stream,
                       x, w, x2, wn, cand, outq, outi);
}